// Round 15
// baseline (88.515 us; speedup 1.0000x reference)
//
#include <hip/hip_runtime.h>

// QuantizeEMAReset forward (eval): VQ quantize + commit loss + perplexity/usage.
// z: [16,4096,64] fp32 -> N=65536 tokens, C=64. codebook: [1024,64] fp32.
// out: [z_q_bar (4194304 f32), commit_loss, ppl, usage] flat.
//
// R15 = R14's barrier-free wave-private-ring skeleton (absmax 0.0) with TWO
// token sets per wave (32 tok/wave, 512 blocks): halves codebook DMA traffic
// (1GB -> 512MB L2) and per-token overhead; 12 MFMAs/tile in 4 independent
// chains. Set B logic is an exact DUPLICATE of the R13-proven path (top-2
// with indices -> keyed merge -> in-lane O(2) exact fp32 rescore) -- NOT
// R9's ballot/whole-wave rescue (the suspect in R9's ppl corruption).
//
// ws float-index map:
//   [0,1024)       cnorm
//   [1024,2048)    counts
//   [2048,2560)    loss partials (512 blocks)
//   [20480,86016)  cbhl tile stream: 64 tiles x 2048 halves (hi 1KB | lo 1KB)

typedef _Float16 half8 __attribute__((ext_vector_type(8)));
typedef float f32x4 __attribute__((ext_vector_type(4)));

#define NTOK 65536
#define KCODE 1024
#define OUT_SCALARS 4194304
#define MARGIN 1e-3f

#define WS_CNT   1024
#define WS_LOSS  2048
#define WS_CBHL  20480

static __device__ __forceinline__ unsigned int order_key(float f) {
    unsigned int u = __float_as_uint(f);
    unsigned int mask = (u >> 31) ? 0xFFFFFFFFu : 0x80000000u;
    return u ^ mask;   // monotone: a<b (float) <=> key(a)<key(b) (uint)
}
static __device__ __forceinline__ float key_to_float(unsigned int k) {
    unsigned int u = (k & 0x80000000u) ? (k ^ 0x80000000u) : ~k;
    return __uint_as_float(u);   // inverse of order_key
}
static __device__ __forceinline__ unsigned long long umin64(unsigned long long a,
                                                            unsigned long long b) {
    return a < b ? a : b;
}
static __device__ __forceinline__ unsigned long long umax64(unsigned long long a,
                                                            unsigned long long b) {
    return a > b ? a : b;
}

__global__ void prep_kernel(const float* __restrict__ cb, float* __restrict__ ws) {
    const int k = blockIdx.x * 256 + threadIdx.x;   // 0..1023
    const float4* cb4 = (const float4*)cb;
    float s = 0.f;
#pragma unroll
    for (int j = 0; j < 16; ++j) {
        float4 v = cb4[k * 16 + j];
        s = fmaf(v.x, v.x, s);
        s = fmaf(v.y, v.y, s);
        s = fmaf(v.z, v.z, s);
        s = fmaf(v.w, v.w, s);
    }
    ws[k] = s;             // cnorm: exact R1 chain
    ws[WS_CNT + k] = 0.f;  // zero histogram

    // swizzled tile stream: tile = k>>4, c = k&15
    _Float16* base = (_Float16*)(ws + WS_CBHL) + (size_t)(k >> 4) * 2048 + (k & 15) * 64;
    const int c = k & 15;
#pragma unroll
    for (int d8 = 0; d8 < 8; ++d8) {
        float4 a = cb4[k * 16 + 2 * d8], b = cb4[k * 16 + 2 * d8 + 1];
        float xf[8] = {a.x, a.y, a.z, a.w, b.x, b.y, b.z, b.w};
        half8 h, lo;
#pragma unroll
        for (int i = 0; i < 8; ++i) {
            _Float16 hi = (_Float16)xf[i];
            h[i] = hi;
            lo[i] = (_Float16)((xf[i] - (float)hi) * 4096.f);  // scaled: no f16 denorm flush
        }
        const int pos = ((d8 + c) & 7) * 8;   // 16B-slot rotation (bank spread)
        *(half8*)(base + pos) = h;
        *(half8*)(base + 1024 + pos) = lo;
    }
}

__launch_bounds__(256, 3)
__global__ void quant_kernel(const float* __restrict__ z,
                             const float* __restrict__ cb,
                             float* __restrict__ out,
                             float* __restrict__ ws) {
    const int t = threadIdx.x, blk = blockIdx.x;
    const int w = t >> 6, l = t & 63;
    const int cl = l & 15, g = l >> 4;
    const int tok0 = blk * 128;
    const int tokW = tok0 + w * 32;          // wave's first token (2 sets of 16)
    const int tokA = tokW + cl;              // set A token (this lane's column)
    const int tokB = tokW + 16 + cl;         // set B token

    __shared__ __align__(16) _Float16 ring[4][3][2048];  // wave-private 3-slot rings, 48KB
    __shared__ __align__(16) float cn_lds[1024];
    __shared__ int win[128];
    __shared__ float lsum[128];

    // ---- stage cnorm to LDS ----
    *(float4*)&cn_lds[t * 4] = *(const float4*)(ws + t * 4);

    // ---- B fragments: TWO token sets of 16 (persistent regs) ----
    half8 zhA[2], zlA[2], zhB[2], zlB[2];
#define MKFRAG(ZH, ZL, TOK)                                                \
    {                                                                      \
        const float4* z4 = (const float4*)z + (size_t)(TOK) * 16;          \
        _Pragma("unroll")                                                  \
        for (int q = 0; q < 2; ++q) {                                      \
            float4 a = z4[2 * g + 8 * q], b = z4[2 * g + 8 * q + 1];       \
            float xf[8] = {a.x, a.y, a.z, a.w, b.x, b.y, b.z, b.w};        \
            _Pragma("unroll")                                              \
            for (int i = 0; i < 8; ++i) {                                  \
                _Float16 h = (_Float16)xf[i];                              \
                ZH[q][i] = h;                                              \
                ZL[q][i] = (_Float16)((xf[i] - (float)h) * 4096.f);        \
            }                                                              \
        }                                                                  \
    }
    MKFRAG(zhA, zlA, tokA)
    MKFRAG(zhB, zlB, tokB)
#undef MKFRAG

    // PIN: z-loads + own LDS writes complete; in-loop vmcnt counts ONLY DMAs.
    asm volatile("s_waitcnt vmcnt(0) lgkmcnt(0)" ::: "memory");
    __builtin_amdgcn_sched_barrier(0);
    __syncthreads();   // cn_lds visible to all waves (ONLY block barrier pre-loop)

    // per-lane DMA src: each wave stages FULL tiles into its own ring
    const char* dma_src = (const char*)(ws + WS_CBHL) + l * 16;
    const int rot = (g + cl) & 7;
    const int o0 = cl * 64 + rot * 8;
    const int o1 = cl * 64 + (rot ^ 4) * 8;

    // prologue: tiles 0,1 in flight (8 DMAs/wave)
#pragma unroll
    for (int p = 0; p < 2; ++p)
#pragma unroll
        for (int q = 0; q < 4; ++q)
            __builtin_amdgcn_global_load_lds(
                (const __attribute__((address_space(1))) void*)(dma_src + p * 4096 + q * 1024),
                (__attribute__((address_space(3))) void*)&ring[w][p][q * 512], 16, 0, 0);

    float d1A = 3.4e38f, d2A = 3.4e38f, d1B = 3.4e38f, d2B = 3.4e38f;
    int i1A = 0, i2A = 0, i1B = 0, i2B = 0;

    // top-2 update (R13-proven select chain; old values, order matters)
#define ARGMIN2(D, KIDX, D1, D2, I1, I2)                                    \
    {                                                                       \
        bool lt = (D) < D1;                                                 \
        bool mid = (D) < D2;                                                \
        I2 = lt ? I1 : (mid ? (KIDX) : I2);                                 \
        D2 = fminf(D2, fmaxf((D), D1));                                     \
        I1 = lt ? (KIDX) : I1;                                              \
        D1 = fminf(D1, (D));                                                \
    }

    // tile T: wait own tile-T DMAs, read frags, issue tile T+2, compute both sets.
#define TILE_BODY(ti, SLOT, VM, ISSUE)                                                \
    {                                                                                 \
        asm volatile("s_waitcnt vmcnt(" VM ")" ::: "memory");                         \
        const _Float16* tp = &ring[w][SLOT][0];                                       \
        half8 H0 = *(const half8*)(tp + o0);                                          \
        half8 H1 = *(const half8*)(tp + o1);                                          \
        half8 L0 = *(const half8*)(tp + 1024 + o0);                                   \
        half8 L1 = *(const half8*)(tp + 1024 + o1);                                   \
        float4 cnv = *(const float4*)&cn_lds[(ti) * 16 + 4 * g];                      \
        const float cna[4] = {cnv.x, cnv.y, cnv.z, cnv.w};                            \
        if (ISSUE) {                                                                  \
            _Pragma("unroll")                                                         \
            for (int q = 0; q < 4; ++q)                                               \
                __builtin_amdgcn_global_load_lds(                                     \
                    (const __attribute__((address_space(1))) void*)(dma_src + ((ti) + 2) * 4096 + q * 1024), \
                    (__attribute__((address_space(3))) void*)&ring[w][((SLOT) + 2) % 3][q * 512], \
                    16, 0, 0);                                                        \
        }                                                                             \
        f32x4 a1A = {0.f,0.f,0.f,0.f}, a2A = {0.f,0.f,0.f,0.f};                       \
        f32x4 a1B = {0.f,0.f,0.f,0.f}, a2B = {0.f,0.f,0.f,0.f};                       \
        a1A = __builtin_amdgcn_mfma_f32_16x16x32_f16(H0, zhA[0], a1A, 0, 0, 0);       \
        a1B = __builtin_amdgcn_mfma_f32_16x16x32_f16(H0, zhB[0], a1B, 0, 0, 0);       \
        a1A = __builtin_amdgcn_mfma_f32_16x16x32_f16(H1, zhA[1], a1A, 0, 0, 0);       \
        a1B = __builtin_amdgcn_mfma_f32_16x16x32_f16(H1, zhB[1], a1B, 0, 0, 0);       \
        a2A = __builtin_amdgcn_mfma_f32_16x16x32_f16(H0, zlA[0], a2A, 0, 0, 0);       \
        a2B = __builtin_amdgcn_mfma_f32_16x16x32_f16(H0, zlB[0], a2B, 0, 0, 0);       \
        a2A = __builtin_amdgcn_mfma_f32_16x16x32_f16(H1, zlA[1], a2A, 0, 0, 0);       \
        a2B = __builtin_amdgcn_mfma_f32_16x16x32_f16(H1, zlB[1], a2B, 0, 0, 0);       \
        a2A = __builtin_amdgcn_mfma_f32_16x16x32_f16(L0, zhA[0], a2A, 0, 0, 0);       \
        a2B = __builtin_amdgcn_mfma_f32_16x16x32_f16(L0, zhB[0], a2B, 0, 0, 0);       \
        a2A = __builtin_amdgcn_mfma_f32_16x16x32_f16(L1, zhA[1], a2A, 0, 0, 0);       \
        a2B = __builtin_amdgcn_mfma_f32_16x16x32_f16(L1, zhB[1], a2B, 0, 0, 0);       \
        _Pragma("unroll")                                                             \
        for (int r = 0; r < 4; ++r) {                                                 \
            const int kidx = (ti) * 16 + 4 * g + r;                                   \
            float dotA = fmaf(a2A[r], 2.44140625e-4f, a1A[r]);                        \
            float dA = fmaf(-2.f, dotA, cna[r]);                                      \
            ARGMIN2(dA, kidx, d1A, d2A, i1A, i2A)                                     \
            float dotB = fmaf(a2B[r], 2.44140625e-4f, a1B[r]);                        \
            float dB = fmaf(-2.f, dotB, cna[r]);                                      \
            ARGMIN2(dB, kidx, d1B, d2B, i1B, i2B)                                     \
        }                                                                             \
    }

    // tiles 0..59 (20 x 3, static ring slots), issuing tiles 2..61
    for (int i3 = 0; i3 < 60; i3 += 3) {
        TILE_BODY(i3 + 0, 0, "4", 1)
        TILE_BODY(i3 + 1, 1, "4", 1)
        TILE_BODY(i3 + 2, 2, "4", 1)
    }
    TILE_BODY(60, 0, "4", 1)   // issues tile 62
    TILE_BODY(61, 1, "4", 1)   // issues tile 63
    TILE_BODY(62, 2, "4", 0)
    TILE_BODY(63, 0, "0", 0)
#undef TILE_BODY
#undef ARGMIN2

    // ---- keyed top-2 merge across the 4 lanes of each token (xor 16, 32) ----
#define MERGE2(K1, K2)                                                      \
    _Pragma("unroll")                                                       \
    for (int off = 16; off <= 32; off <<= 1) {                              \
        unsigned long long ok1 = __shfl_xor(K1, off, 64);                   \
        unsigned long long ok2 = __shfl_xor(K2, off, 64);                   \
        unsigned long long lo = umin64(K1, ok1);                            \
        unsigned long long hi = umax64(K1, ok1);                            \
        K2 = umin64(hi, umin64(K2, ok2));                                   \
        K1 = lo;                                                            \
    }
    unsigned long long k1A = ((unsigned long long)order_key(d1A) << 32) | (unsigned)i1A;
    unsigned long long k2A = ((unsigned long long)order_key(d2A) << 32) | (unsigned)i2A;
    unsigned long long k1B = ((unsigned long long)order_key(d1B) << 32) | (unsigned)i1B;
    unsigned long long k2B = ((unsigned long long)order_key(d2B) << 32) | (unsigned)i2B;
    MERGE2(k1A, k2A)
    MERGE2(k1B, k2B)
#undef MERGE2

    // ---- per-set: near-tie -> in-lane O(2) exact fp32 rescore (R13-proven) ----
#define RESOLVE(K1, K2, TOK, FIDX)                                          \
    int FIDX = (int)(unsigned)(K1 & 0xFFFFFFFFull);                         \
    {                                                                       \
        const float d1f = key_to_float((unsigned)(K1 >> 32));               \
        const float d2f = key_to_float((unsigned)(K2 >> 32));               \
        if (d2f - d1f < MARGIN) {                                           \
            const int ia = FIDX;                                            \
            const int ib = (int)(unsigned)(K2 & 0xFFFFFFFFull);             \
            const float4* zr = (const float4*)z + (size_t)(TOK) * 16;       \
            const float4* ca = (const float4*)cb + (size_t)ia * 16;         \
            const float4* cbp = (const float4*)cb + (size_t)ib * 16;        \
            float sa = 0.f, sb = 0.f;                                       \
            _Pragma("unroll")                                               \
            for (int j = 0; j < 16; ++j) {                                  \
                float4 xv = zr[j];                                          \
                float4 va = ca[j], vb = cbp[j];                             \
                sa = fmaf(xv.x, va.x, sa); sb = fmaf(xv.x, vb.x, sb);       \
                sa = fmaf(xv.y, va.y, sa); sb = fmaf(xv.y, vb.y, sb);       \
                sa = fmaf(xv.z, va.z, sa); sb = fmaf(xv.z, vb.z, sb);       \
                sa = fmaf(xv.w, va.w, sa); sb = fmaf(xv.w, vb.w, sb);       \
            }                                                               \
            const float ea = fmaf(-2.f, sa, cn_lds[ia]);                    \
            const float eb = fmaf(-2.f, sb, cn_lds[ib]);                    \
            const unsigned long long ka =                                   \
                ((unsigned long long)order_key(ea) << 32) | (unsigned)ia;   \
            const unsigned long long kb =                                   \
                ((unsigned long long)order_key(eb) << 32) | (unsigned)ib;   \
            FIDX = (int)(unsigned)(umin64(ka, kb) & 0xFFFFFFFFull);         \
        }                                                                   \
    }

    if (l < 16) {
        RESOLVE(k1A, k2A, tokA, fidxA)
        RESOLVE(k1B, k2B, tokB, fidxB)
        win[w * 32 + l] = fidxA;
        win[w * 32 + 16 + l] = fidxB;
        atomicAdd(&ws[WS_CNT + fidxA], 1.f);   // integer-valued: exact, order-indep
        atomicAdd(&ws[WS_CNT + fidxB], 1.f);
    }
#undef RESOLVE
    __syncthreads();

    // ---- fused epilogue: z_q_bar + commit-loss partial (z re-read, L2-hot) ----
    {
        const int lt = t >> 1, h = t & 1;       // 2 threads per token
        const int tokE = tok0 + lt;
        const int idx = win[lt];
        const float4* zr = (const float4*)z + (size_t)tokE * 16 + h * 8;
        const float4* cq = (const float4*)cb + (size_t)idx * 16 + h * 8;
        float4* o4 = (float4*)out + (size_t)tokE * 16 + h * 8;
        float ss = 0.f;
#pragma unroll
        for (int j = 0; j < 8; ++j) {
            float4 xv = zr[j];
            float4 qv = cq[j];
            float4 ov; float dx;
            dx = qv.x - xv.x; ov.x = xv.x + dx; ss = fmaf(dx, dx, ss);
            dx = qv.y - xv.y; ov.y = xv.y + dx; ss = fmaf(dx, dx, ss);
            dx = qv.z - xv.z; ov.z = xv.z + dx; ss = fmaf(dx, dx, ss);
            dx = qv.w - xv.w; ov.w = xv.w + dx; ss = fmaf(dx, dx, ss);
            o4[j] = ov;
        }
        float os = __shfl_down(ss, 1, 64);      // partner lane (same token)
        if (h == 0) lsum[lt] = (ss + os) * (1.f / 64.f);
    }
    __syncthreads();
    if (t < 64) {
        float v = lsum[t] + lsum[t + 64];
#pragma unroll
        for (int off = 32; off > 0; off >>= 1) v += __shfl_down(v, off, 64);
        if (t == 0) ws[WS_LOSS + blk] = v;
    }
}

// Reduce-only final (shuffle trees; R12/R13-proven logic). 1 block x 1024 thr.
__global__ void final_kernel(const float* __restrict__ ws, float* __restrict__ out) {
    const int t = threadIdx.x;          // 0..1023
    const int l = t & 63, wv = t >> 6;  // 16 waves
    __shared__ float rbuf[16];

#define BLOCK_REDUCE(VAR, EXPR)                                             \
    float VAR;                                                              \
    {                                                                       \
        float v_ = (EXPR);                                                  \
        _Pragma("unroll")                                                   \
        for (int off = 32; off > 0; off >>= 1) v_ += __shfl_down(v_, off, 64); \
        if (l == 0) rbuf[wv] = v_;                                          \
        __syncthreads();                                                    \
        float r_ = (t < 16) ? rbuf[t] : 0.f;                                \
        if (wv == 0) {                                                      \
            _Pragma("unroll")                                               \
            for (int off = 8; off > 0; off >>= 1) r_ += __shfl_down(r_, off, 64); \
            if (l == 0) rbuf[0] = r_;                                       \
        }                                                                   \
        __syncthreads();                                                    \
        VAR = rbuf[0];                                                      \
        __syncthreads();                                                    \
    }

    const float c = ws[WS_CNT + t];
    BLOCK_REDUCE(totraw, c)
    const float total = fmaxf(totraw, 1e-6f);
    const float p = c / total;
    BLOCK_REDUCE(ent, p * logf(p + 1e-7f))
    BLOCK_REDUCE(used, (c >= 1.f) ? 1.f : 0.f)
    BLOCK_REDUCE(loss, (t < 512) ? ws[WS_LOSS + t] : 0.f)
#undef BLOCK_REDUCE

    if (t == 0) {
        out[OUT_SCALARS + 0] = loss * (1.f / (float)NTOK);
        out[OUT_SCALARS + 1] = expf(-ent);
        out[OUT_SCALARS + 2] = used * (1.f / (float)KCODE);
    }
}

extern "C" void kernel_launch(void* const* d_in, const int* in_sizes, int n_in,
                              void* d_out, int out_size, void* d_ws, size_t ws_size,
                              hipStream_t stream) {
    const float* z  = (const float*)d_in[0];
    const float* cb = (const float*)d_in[1];
    float* out = (float*)d_out;
    float* ws  = (float*)d_ws;   // ~344 KB used

    prep_kernel <<<4, 256, 0, stream>>>(cb, ws);
    quant_kernel<<<NTOK / 128, 256, 0, stream>>>(z, cb, out, ws);
    final_kernel<<<1, 1024, 0, stream>>>(ws, out);
}